// Round 5
// baseline (1430.517 us; speedup 1.0000x reference)
//
#include <hip/hip_runtime.h>

using f32x4  = __attribute__((ext_vector_type(4))) float;
using bf16x8 = __attribute__((ext_vector_type(8))) __bf16;
using u16x4  = __attribute__((ext_vector_type(4))) unsigned short;

#define BK 64
#define REG_HALF   8192      // ushorts: 128 rows x 64 cols
#define A_OFS      0
#define B_OFS      16384
#define BUF_STRIDE 32768     // one buffer = A(32KB)+B(32KB) = 64 KB

#define BARRIER() asm volatile("s_barrier" ::: "memory")

__device__ __forceinline__ unsigned short f32_to_bf16_bits(float f) {
    unsigned int u = __builtin_bit_cast(unsigned int, f);
    u = (u + 0x7fffu + ((u >> 16) & 1u)) >> 16;
    return (unsigned short)u;
}

__device__ __forceinline__ void gload_lds16(const void* g, void* l) {
    __builtin_amdgcn_global_load_lds(
        (const __attribute__((address_space(1))) unsigned int*)g,
        (__attribute__((address_space(3))) unsigned int*)l,
        16, 0, 0);
}

// ---------------------------------------------------------------------------
// Fake-quant x (exact-f32 math, bf16 store) and W f32->bf16. Unchanged.
// ---------------------------------------------------------------------------
__global__ void quant_kernel(const float* __restrict__ x,
                             unsigned short* __restrict__ xq,
                             int total4) {
    int idx = blockIdx.x * 256 + threadIdx.x;
    if (idx >= total4) return;
    f32x4 v = *(const f32x4*)(x + (size_t)idx * 4);
    float am = fmaxf(fmaxf(fabsf(v[0]), fabsf(v[1])),
                     fmaxf(fabsf(v[2]), fabsf(v[3])));
    am = fmaxf(am, __shfl_xor(am, 1));
    am = fmaxf(am, __shfl_xor(am, 2));
    am = fmaxf(am, __shfl_xor(am, 4));
    am = fmaxf(am, __shfl_xor(am, 8));
    float delta = fmaxf(am / 127.0f, 1e-5f);
    u16x4 o;
#pragma unroll
    for (int i = 0; i < 4; ++i) {
        float q = rintf(v[i] / delta);
        q = fminf(fmaxf(q, -127.0f), 127.0f);
        o[i] = f32_to_bf16_bits(q * delta);
    }
    *(u16x4*)(xq + (size_t)idx * 4) = o;
}

__global__ void wconv_kernel(const float* __restrict__ W,
                             unsigned short* __restrict__ Wb,
                             int total4) {
    int idx = blockIdx.x * 256 + threadIdx.x;
    if (idx >= total4) return;
    f32x4 v = *(const f32x4*)(W + (size_t)idx * 4);
    u16x4 o;
#pragma unroll
    for (int i = 0; i < 4; ++i) o[i] = f32_to_bf16_bits(v[i]);
    *(u16x4*)(Wb + (size_t)idx * 4) = o;
}

// ---------------------------------------------------------------------------
// Staging: one 16 KB half-region per call, 2 x gload_lds(16B)/thread.
// LDS dest LINEAR; T2 swizzle + region row-permutation on GLOBAL src addr.
//   A: tile row = (gr>>6)*128 + h*64 + (gr&63)   (h0 = m-frags 0-3)
//   B: tile row = (gr>>5)*64  + h*32 + (gr&31)   (h0 = n-frags 0-1)
// ---------------------------------------------------------------------------
__device__ __forceinline__ void stage_A_half(
    const unsigned short* __restrict__ G, int K,
    unsigned short* lds_region, int h, int tid)
{
#pragma unroll
    for (int it = 0; it < 2; ++it) {
        int g  = it * 512 + tid;
        int gr = g >> 3;
        int c  = ((g & 7) ^ (gr & 7)) << 3;
        int r  = ((gr >> 6) << 7) + h * 64 + (gr & 63);
        gload_lds16(G + (size_t)r * K + c, lds_region + g * 8);
    }
}

__device__ __forceinline__ void stage_B_half(
    const unsigned short* __restrict__ G, int K,
    unsigned short* lds_region, int h, int tid)
{
#pragma unroll
    for (int it = 0; it < 2; ++it) {
        int g  = it * 512 + tid;
        int gr = g >> 3;
        int c  = ((g & 7) ^ (gr & 7)) << 3;
        int r  = ((gr >> 5) << 6) + h * 32 + (gr & 31);
        gload_lds16(G + (size_t)r * K + c, lds_region + g * 8);
    }
}

// Fragment readers (region base pointer; swizzled column) ------------------
__device__ __forceinline__ void read_af(bf16x8 (&dst)[4][2],
    const unsigned short* reg, int wm, int lr, int lk, int sx) {
#pragma unroll
    for (int m = 0; m < 4; ++m)
#pragma unroll
        for (int kk = 0; kk < 2; ++kk)
            dst[m][kk] = *(const bf16x8*)(reg
                + (wm * 64 + m * 16 + lr) * 64 + ((((kk << 2) + lk) ^ sx) << 3));
}

__device__ __forceinline__ void read_bf(bf16x8 (&dst)[2][2],
    const unsigned short* reg, int wn, int lr, int lk, int sx) {
#pragma unroll
    for (int n = 0; n < 2; ++n)
#pragma unroll
        for (int kk = 0; kk < 2; ++kk)
            dst[n][kk] = *(const bf16x8*)(reg
                + (wn * 32 + n * 16 + lr) * 64 + ((((kk << 2) + lk) ^ sx) << 3));
}

__device__ __forceinline__ void mfma_quad(f32x4 (&acc)[8][4], int mo, int no,
    const bf16x8 (&af)[4][2], const bf16x8 (&bf)[2][2]) {
#pragma unroll
    for (int m = 0; m < 4; ++m)
#pragma unroll
        for (int n = 0; n < 2; ++n)
#pragma unroll
            for (int kk = 0; kk < 2; ++kk)
                acc[mo + m][no + n] = __builtin_amdgcn_mfma_f32_16x16x32_bf16(
                    af[m][kk], bf[n][kk], acc[mo + m][no + n], 0, 0, 0);
}

// ---------------------------------------------------------------------------
// 256x256 bf16 GEMM (B^T), cross-tile register-pipelined schedule.
// Per tile: [issue bfH,afH reads + stage t+1h1] Q1(from regs) vmcnt(4) BAR
//           [stage t+2h0] Q2 [issue afL'(t+1)] Q3 [issue bfA'(t+1)] Q4
//           vmcnt(4) BAR.
// vmcnt ledger (2 loads/thread per stage call): mid point outstanding =
// {t+1h0(4), t+1h1(4)} -> vmcnt(4) proves t+1h0 landed (read after BAR);
// boundary outstanding = {t+1h1(4), t+2h0(4)} -> vmcnt(4) proves t+1 done.
// Q1 frags (afL,bfA) rotate across tiles in registers; their ~1150cyc LDS
// delivery hides under Q3+Q4's ~1860cyc MFMA. sched_barrier(0) pins read
// issues before MFMA clusters (rule 18). 2 barriers/tile; vmcnt(0) only at
// the tail.
// ---------------------------------------------------------------------------
__global__ __launch_bounds__(512, 2) void gemm_kernel(
    const unsigned short* __restrict__ A,   // [M][K] bf16 bits (quantized x)
    const unsigned short* __restrict__ B,   // [N][K] bf16 bits (W)
    const float* __restrict__ bias,         // [N]
    float* __restrict__ out,                // [M][N] f32
    int M, int N, int K)
{
    __shared__ unsigned short lds[2 * BUF_STRIDE];   // 128 KiB

    const int tid  = threadIdx.x;
    const int lane = tid & 63;
    const int wv   = tid >> 6;
    const int wm   = wv >> 2;        // 0..1  (128 rows each)
    const int wn   = wv & 3;         // 0..3  (64 cols each)
    const int lr   = lane & 15;
    const int lk   = lane >> 4;      // 0..3
    const int sx   = lr & 7;

    const int nbn = N / 256;
    const int nwg = gridDim.x;
    const int cpx = nwg >> 3;        // bijective XCD swizzle (nwg % 8 == 0)
    const int swz = (blockIdx.x & 7) * cpx + (blockIdx.x >> 3);
    const int bm0 = (swz / nbn) * 256;
    const int bn0 = (swz % nbn) * 256;

    const unsigned short* Ag = A + (size_t)bm0 * K;
    const unsigned short* Bg = B + (size_t)bn0 * K;
    const int NT = K / BK;           // 64 (even -> clean x2 unroll)

    f32x4 acc[8][4] = {};

    // Prologue: tile0 full (8 loads) + tile1 h0 (4 loads).
    stage_A_half(Ag,      K, lds + A_OFS,              0, tid);
    stage_A_half(Ag,      K, lds + A_OFS + REG_HALF,   1, tid);
    stage_B_half(Bg,      K, lds + B_OFS,              0, tid);
    stage_B_half(Bg,      K, lds + B_OFS + REG_HALF,   1, tid);
    stage_A_half(Ag + BK, K, lds + BUF_STRIDE + A_OFS, 0, tid);
    stage_B_half(Bg + BK, K, lds + BUF_STRIDE + B_OFS, 0, tid);
    asm volatile("s_waitcnt vmcnt(4)" ::: "memory");   // tile0 landed
    BARRIER();

    bf16x8 afA[4][2], bfAa[2][2], afB[4][2], bfBb[2][2];
    read_af(afA,  lds + A_OFS, wm, lr, lk, sx);        // tile0 Q1 frags
    read_bf(bfAa, lds + B_OFS, wn, lr, lk, sx);

#define TILE_ITER(T, CB, NB, AFI, BFI, AFO, BFO)                               \
    {                                                                          \
        unsigned short* cb_ = (CB);                                            \
        unsigned short* nb_ = (NB);                                            \
        bf16x8 bfH_[2][2], afH_[4][2];                                         \
        read_bf(bfH_, cb_ + B_OFS + REG_HALF, wn, lr, lk, sx);                 \
        read_af(afH_, cb_ + A_OFS + REG_HALF, wm, lr, lk, sx);                 \
        if ((T) + 1 < NT) {                                                    \
            stage_A_half(Ag + (size_t)((T)+1) * BK, K, nb_ + A_OFS + REG_HALF, 1, tid); \
            stage_B_half(Bg + (size_t)((T)+1) * BK, K, nb_ + B_OFS + REG_HALF, 1, tid); \
        }                                                                      \
        __builtin_amdgcn_sched_barrier(0);                                     \
        __builtin_amdgcn_s_setprio(1);                                         \
        mfma_quad(acc, 0, 0, AFI, BFI);           /* Q1 */                     \
        __builtin_amdgcn_s_setprio(0);                                         \
        asm volatile("s_waitcnt vmcnt(4)" ::: "memory");                       \
        BARRIER();                                                             \
        if ((T) + 2 < NT) {                                                    \
            stage_A_half(Ag + (size_t)((T)+2) * BK, K, cb_ + A_OFS, 0, tid);   \
            stage_B_half(Bg + (size_t)((T)+2) * BK, K, cb_ + B_OFS, 0, tid);   \
        }                                                                      \
        __builtin_amdgcn_sched_barrier(0);                                     \
        __builtin_amdgcn_s_setprio(1);                                         \
        mfma_quad(acc, 0, 2, AFI, bfH_);          /* Q2 */                     \
        __builtin_amdgcn_s_setprio(0);                                         \
        if ((T) + 1 < NT) read_af(AFO, nb_ + A_OFS, wm, lr, lk, sx);           \
        __builtin_amdgcn_sched_barrier(0);                                     \
        __builtin_amdgcn_s_setprio(1);                                         \
        mfma_quad(acc, 4, 0, afH_, BFI);          /* Q3 */                     \
        __builtin_amdgcn_s_setprio(0);                                         \
        if ((T) + 1 < NT) read_bf(BFO, nb_ + B_OFS, wn, lr, lk, sx);           \
        __builtin_amdgcn_sched_barrier(0);                                     \
        __builtin_amdgcn_s_setprio(1);                                         \
        mfma_quad(acc, 4, 2, afH_, bfH_);         /* Q4 */                     \
        __builtin_amdgcn_s_setprio(0);                                         \
        if ((T) + 2 < NT) asm volatile("s_waitcnt vmcnt(4)" ::: "memory");     \
        else              asm volatile("s_waitcnt vmcnt(0)" ::: "memory");     \
        BARRIER();                                                             \
    }

    for (int tt = 0; tt < NT; tt += 2) {
        TILE_ITER(tt,     lds,              lds + BUF_STRIDE, afA, bfAa, afB, bfBb);
        TILE_ITER(tt + 1, lds + BUF_STRIDE, lds,              afB, bfBb, afA, bfAa);
    }
#undef TILE_ITER

    // Epilogue: C/D layout col = lane&15, row = (lane>>4)*4 + j  [m89]
    const int r0   = bm0 + wm * 128;
    const int c0   = bn0 + wn * 64;
    const int rsub = lk << 2;
#pragma unroll
    for (int nf = 0; nf < 4; ++nf) {
        int col = c0 + nf * 16 + lr;
        float bv = bias[col];
#pragma unroll
        for (int mf = 0; mf < 8; ++mf) {
            int row = r0 + mf * 16 + rsub;
#pragma unroll
            for (int j = 0; j < 4; ++j)
                out[(size_t)(row + j) * N + col] = acc[mf][nf][j] + bv;
        }
    }
}

extern "C" void kernel_launch(void* const* d_in, const int* in_sizes, int n_in,
                              void* d_out, int out_size, void* d_ws, size_t ws_size,
                              hipStream_t stream) {
    const float* x = (const float*)d_in[0];   // [M][K] f32
    const float* W = (const float*)d_in[1];   // [N][K] f32
    const float* b = (const float*)d_in[2];   // [N]   f32
    float* out = (float*)d_out;               // [M][N] f32

    const int N = in_sizes[2];                // 4096
    const int K = in_sizes[1] / N;            // 4096
    const int M = in_sizes[0] / K;            // 8192

    unsigned short* xq = (unsigned short*)d_ws;            // 64 MB
    unsigned short* Wb = xq + (size_t)M * K;               // 32 MB

    const int t4x = (int)(((long long)M * K) / 4);
    quant_kernel<<<(t4x + 255) / 256, 256, 0, stream>>>(x, xq, t4x);
    const int t4w = (int)(((long long)N * K) / 4);
    wconv_kernel<<<(t4w + 255) / 256, 256, 0, stream>>>(W, Wb, t4w);

    dim3 grid((M / 256) * (N / 256));         // 512 blocks
    gemm_kernel<<<grid, 512, 0, stream>>>(xq, Wb, b, out, M, N, K);
}

// Round 6
// 287.873 us; speedup vs baseline: 4.9693x; 4.9693x over previous
//
#include <hip/hip_runtime.h>

using f32x4  = __attribute__((ext_vector_type(4))) float;
using bf16x8 = __attribute__((ext_vector_type(8))) __bf16;
using u16x4  = __attribute__((ext_vector_type(4))) unsigned short;

#define BK 64
#define REG_HALF   8192      // ushorts: 128 rows x 64 cols
#define A_OFS      0
#define B_OFS      16384
#define BUF_STRIDE 32768     // one buffer = A(32KB)+B(32KB) = 64 KB

#define BARRIER() asm volatile("s_barrier" ::: "memory")
#define VMCNT4()  asm volatile("s_waitcnt vmcnt(4)" ::: "memory")

__device__ __forceinline__ unsigned short f32_to_bf16_bits(float f) {
    unsigned int u = __builtin_bit_cast(unsigned int, f);
    u = (u + 0x7fffu + ((u >> 16) & 1u)) >> 16;
    return (unsigned short)u;
}

__device__ __forceinline__ void gload_lds16(const void* g, void* l) {
    __builtin_amdgcn_global_load_lds(
        (const __attribute__((address_space(1))) unsigned int*)g,
        (__attribute__((address_space(3))) unsigned int*)l,
        16, 0, 0);
}

// ---------------------------------------------------------------------------
// Fake-quant x (exact-f32 math, bf16 store) and W f32->bf16. Unchanged.
// ---------------------------------------------------------------------------
__global__ void quant_kernel(const float* __restrict__ x,
                             unsigned short* __restrict__ xq,
                             int total4) {
    int idx = blockIdx.x * 256 + threadIdx.x;
    if (idx >= total4) return;
    f32x4 v = *(const f32x4*)(x + (size_t)idx * 4);
    float am = fmaxf(fmaxf(fabsf(v[0]), fabsf(v[1])),
                     fmaxf(fabsf(v[2]), fabsf(v[3])));
    am = fmaxf(am, __shfl_xor(am, 1));
    am = fmaxf(am, __shfl_xor(am, 2));
    am = fmaxf(am, __shfl_xor(am, 4));
    am = fmaxf(am, __shfl_xor(am, 8));
    float delta = fmaxf(am / 127.0f, 1e-5f);
    u16x4 o;
#pragma unroll
    for (int i = 0; i < 4; ++i) {
        float q = rintf(v[i] / delta);
        q = fminf(fmaxf(q, -127.0f), 127.0f);
        o[i] = f32_to_bf16_bits(q * delta);
    }
    *(u16x4*)(xq + (size_t)idx * 4) = o;
}

__global__ void wconv_kernel(const float* __restrict__ W,
                             unsigned short* __restrict__ Wb,
                             int total4) {
    int idx = blockIdx.x * 256 + threadIdx.x;
    if (idx >= total4) return;
    f32x4 v = *(const f32x4*)(W + (size_t)idx * 4);
    u16x4 o;
#pragma unroll
    for (int i = 0; i < 4; ++i) o[i] = f32_to_bf16_bits(v[i]);
    *(u16x4*)(Wb + (size_t)idx * 4) = o;
}

// ---------------------------------------------------------------------------
// Staging: one 16 KB half-region per call, 2 x gload_lds(16B)/thread.
// LDS dest LINEAR; T2 swizzle + region row-permutation on GLOBAL src addr.
//   A: tile row = (gr>>6)*128 + h*64 + (gr&63)   (h0 = m-frags 0-3 per wm)
//   B: tile row = (gr>>5)*64  + h*32 + (gr&31)   (h0 = n-frags 0-1 per wn)
// ---------------------------------------------------------------------------
__device__ __forceinline__ void stage_A_half(
    const unsigned short* __restrict__ G, int K,
    unsigned short* lds_region, int h, int tid)
{
#pragma unroll
    for (int it = 0; it < 2; ++it) {
        int g  = it * 512 + tid;
        int gr = g >> 3;
        int c  = ((g & 7) ^ (gr & 7)) << 3;
        int r  = ((gr >> 6) << 7) + h * 64 + (gr & 63);
        gload_lds16(G + (size_t)r * K + c, lds_region + g * 8);
    }
}

__device__ __forceinline__ void stage_B_half(
    const unsigned short* __restrict__ G, int K,
    unsigned short* lds_region, int h, int tid)
{
#pragma unroll
    for (int it = 0; it < 2; ++it) {
        int g  = it * 512 + tid;
        int gr = g >> 3;
        int c  = ((g & 7) ^ (gr & 7)) << 3;
        int r  = ((gr >> 5) << 6) + h * 32 + (gr & 31);
        gload_lds16(G + (size_t)r * K + c, lds_region + g * 8);
    }
}

// Fragment readers (region base pointer; T2-swizzled column) ---------------
__device__ __forceinline__ void read_af(bf16x8 (&dst)[4][2],
    const unsigned short* reg, int wm, int lr, int lk, int sx) {
#pragma unroll
    for (int m = 0; m < 4; ++m)
#pragma unroll
        for (int kk = 0; kk < 2; ++kk)
            dst[m][kk] = *(const bf16x8*)(reg
                + (wm * 64 + m * 16 + lr) * 64 + ((((kk << 2) + lk) ^ sx) << 3));
}

__device__ __forceinline__ void read_bf(bf16x8 (&dst)[2][2],
    const unsigned short* reg, int wn, int lr, int lk, int sx) {
#pragma unroll
    for (int n = 0; n < 2; ++n)
#pragma unroll
        for (int kk = 0; kk < 2; ++kk)
            dst[n][kk] = *(const bf16x8*)(reg
                + (wn * 32 + n * 16 + lr) * 64 + ((((kk << 2) + lk) ^ sx) << 3));
}

__device__ __forceinline__ void mfma_quad(f32x4 (&acc)[8][4], int mo, int no,
    const bf16x8 (&af)[4][2], const bf16x8 (&bf)[2][2]) {
#pragma unroll
    for (int m = 0; m < 4; ++m)
#pragma unroll
        for (int n = 0; n < 2; ++n)
#pragma unroll
            for (int kk = 0; kk < 2; ++kk)
                acc[mo + m][no + n] = __builtin_amdgcn_mfma_f32_16x16x32_bf16(
                    af[m][kk], bf[n][kk], acc[mo + m][no + n], 0, 0, 0);
}

// ---------------------------------------------------------------------------
// 256x256 bf16 GEMM (B^T), m201-faithful 4-phase/tile schedule.
// Phase = { reads(this quad) ; stage(1 half-region) ; sched_barrier ;
//           BARRIER ; setprio(1) 16xMFMA setprio(0) ; [vmcnt(4)] ; BARRIER }
// Stage stream s(t,q): q1: B-h0(t+1)->nb, q2: A-h1(t+1)->nb,
//                      q3: B-h1(t+1)->nb, q4: A-h0(t+2)->cb.
// Reads: P1 afL=A-h0(t) [s(t-2,4)], P2 bfB=B-h1(t) [s(t-1,3)],
//        P3 afH=A-h1(t) [s(t-1,2)], P4 bfA'=B-h0(t+1) [s(t,1)] (rotates).
// vmcnt(4) before P1's and P3's trailing barriers only (ledger: 8
// outstanding -> retire oldest 2 calls; vmcnt-before-barrier makes the
// proof cross-wave). Tail: stage sources clamped to NT-1 -> ledger exact,
// redundant writes land in dead regions, final bfA' read is unused.
// Frag budget: peak ~20 live b128 (80 V) -> fits the 128-VGPR cap at
// 2 waves/SIMD (acc=128 AGPR). No deep rotation (round-5 spill lesson).
// ---------------------------------------------------------------------------
__global__ __launch_bounds__(512, 2) void gemm_kernel(
    const unsigned short* __restrict__ A,   // [M][K] bf16 bits (quantized x)
    const unsigned short* __restrict__ B,   // [N][K] bf16 bits (W)
    const float* __restrict__ bias,         // [N]
    float* __restrict__ out,                // [M][N] f32
    int M, int N, int K)
{
    __shared__ unsigned short lds[2 * BUF_STRIDE];   // 128 KiB

    const int tid  = threadIdx.x;
    const int lane = tid & 63;
    const int wv   = tid >> 6;
    const int wm   = wv >> 2;        // 0..1  (128 rows each)
    const int wn   = wv & 3;         // 0..3  (64 cols each)
    const int lr   = lane & 15;
    const int lk   = lane >> 4;      // 0..3
    const int sx   = lr & 7;

    const int nbn = N / 256;
    const int nwg = gridDim.x;
    const int cpx = nwg >> 3;        // bijective XCD swizzle (nwg % 8 == 0)
    const int swz = (blockIdx.x & 7) * cpx + (blockIdx.x >> 3);
    const int bm0 = (swz / nbn) * 256;
    const int bn0 = (swz % nbn) * 256;

    const unsigned short* Ag = A + (size_t)bm0 * K;
    const unsigned short* Bg = B + (size_t)bn0 * K;
    const int NT = K / BK;           // 64, even

    f32x4 acc[8][4] = {};

    // Prologue: c1..c5 then vmcnt(6): 10 outstanding -> retire c1,c2
    // (A-h0(0), B-h0(0) proven); BARRIER makes it cross-wave.
    stage_A_half(Ag,      K, lds + A_OFS,              0, tid);  // c1
    stage_B_half(Bg,      K, lds + B_OFS,              0, tid);  // c2
    stage_A_half(Ag,      K, lds + A_OFS + REG_HALF,   1, tid);  // c3
    stage_B_half(Bg,      K, lds + B_OFS + REG_HALF,   1, tid);  // c4
    stage_A_half(Ag + BK, K, lds + BUF_STRIDE + A_OFS, 0, tid);  // c5
    asm volatile("s_waitcnt vmcnt(6)" ::: "memory");
    BARRIER();

    bf16x8 bfA_e[2][2], bfA_o[2][2];
    read_bf(bfA_e, lds + B_OFS, wn, lr, lk, sx);     // bfA(0)

#define TILE_ITER(T, CB, NB, BFA_IN, BFA_OUT)                                  \
    {                                                                          \
        unsigned short* cb_ = (CB);                                            \
        unsigned short* nb_ = (NB);                                            \
        const int t1_ = ((T) + 1 < NT) ? (T) + 1 : NT - 1;                     \
        const int t2_ = ((T) + 2 < NT) ? (T) + 2 : NT - 1;                     \
        bf16x8 afL_[4][2], afH_[4][2], bfB_[2][2];                             \
        /* P1: Q1 = afL x bfA_in */                                            \
        read_af(afL_, cb_ + A_OFS, wm, lr, lk, sx);                            \
        stage_B_half(Bg + (size_t)t1_ * BK, K, nb_ + B_OFS, 0, tid);           \
        __builtin_amdgcn_sched_barrier(0);                                     \
        BARRIER();                                                             \
        __builtin_amdgcn_s_setprio(1);                                         \
        mfma_quad(acc, 0, 0, afL_, BFA_IN);                                    \
        __builtin_amdgcn_s_setprio(0);                                         \
        VMCNT4();                      /* proves s(t-1,2), s(t-1,3) */         \
        BARRIER();                                                             \
        /* P2: Q2 = afL x bfB */                                               \
        read_bf(bfB_, cb_ + B_OFS + REG_HALF, wn, lr, lk, sx);                 \
        stage_A_half(Ag + (size_t)t1_ * BK, K, nb_ + A_OFS + REG_HALF, 1, tid);\
        __builtin_amdgcn_sched_barrier(0);                                     \
        BARRIER();                                                             \
        __builtin_amdgcn_s_setprio(1);                                         \
        mfma_quad(acc, 0, 2, afL_, bfB_);                                      \
        __builtin_amdgcn_s_setprio(0);                                         \
        BARRIER();                                                             \
        /* P3: Q3 = afH x bfA_in */                                            \
        read_af(afH_, cb_ + A_OFS + REG_HALF, wm, lr, lk, sx);                 \
        stage_B_half(Bg + (size_t)t1_ * BK, K, nb_ + B_OFS + REG_HALF, 1, tid);\
        __builtin_amdgcn_sched_barrier(0);                                     \
        BARRIER();                                                             \
        __builtin_amdgcn_s_setprio(1);                                         \
        mfma_quad(acc, 4, 0, afH_, BFA_IN);                                    \
        __builtin_amdgcn_s_setprio(0);                                         \
        VMCNT4();                      /* proves s(t-1,4), s(t,1) */           \
        BARRIER();                                                             \
        /* P4: Q4 = afH x bfB; rotate bfA' for next tile */                    \
        read_bf(BFA_OUT, nb_ + B_OFS, wn, lr, lk, sx);                         \
        stage_A_half(Ag + (size_t)t2_ * BK, K, cb_ + A_OFS, 0, tid);           \
        __builtin_amdgcn_sched_barrier(0);                                     \
        BARRIER();                                                             \
        __builtin_amdgcn_s_setprio(1);                                         \
        mfma_quad(acc, 4, 2, afH_, bfB_);                                      \
        __builtin_amdgcn_s_setprio(0);                                         \
        BARRIER();                                                             \
    }

    for (int tt = 0; tt < NT; tt += 2) {
        TILE_ITER(tt,     lds,              lds + BUF_STRIDE, bfA_e, bfA_o);
        TILE_ITER(tt + 1, lds + BUF_STRIDE, lds,              bfA_o, bfA_e);
    }
#undef TILE_ITER

    // Epilogue: C/D layout col = lane&15, row = (lane>>4)*4 + j  [m89]
    const int r0   = bm0 + wm * 128;
    const int c0   = bn0 + wn * 64;
    const int rsub = lk << 2;
#pragma unroll
    for (int nf = 0; nf < 4; ++nf) {
        int col = c0 + nf * 16 + lr;
        float bv = bias[col];
#pragma unroll
        for (int mf = 0; mf < 8; ++mf) {
            int row = r0 + mf * 16 + rsub;
#pragma unroll
            for (int j = 0; j < 4; ++j)
                out[(size_t)(row + j) * N + col] = acc[mf][nf][j] + bv;
        }
    }
}

extern "C" void kernel_launch(void* const* d_in, const int* in_sizes, int n_in,
                              void* d_out, int out_size, void* d_ws, size_t ws_size,
                              hipStream_t stream) {
    const float* x = (const float*)d_in[0];   // [M][K] f32
    const float* W = (const float*)d_in[1];   // [N][K] f32
    const float* b = (const float*)d_in[2];   // [N]   f32
    float* out = (float*)d_out;               // [M][N] f32

    const int N = in_sizes[2];                // 4096
    const int K = in_sizes[1] / N;            // 4096
    const int M = in_sizes[0] / K;            // 8192

    unsigned short* xq = (unsigned short*)d_ws;            // 64 MB
    unsigned short* Wb = xq + (size_t)M * K;               // 32 MB

    const int t4x = (int)(((long long)M * K) / 4);
    quant_kernel<<<(t4x + 255) / 256, 256, 0, stream>>>(x, xq, t4x);
    const int t4w = (int)(((long long)N * K) / 4);
    wconv_kernel<<<(t4w + 255) / 256, 256, 0, stream>>>(W, Wb, t4w);

    dim3 grid((M / 256) * (N / 256));         // 512 blocks
    gemm_kernel<<<grid, 512, 0, stream>>>(xq, Wb, b, out, M, N, K);
}

// Round 7
// 275.252 us; speedup vs baseline: 5.1971x; 1.0459x over previous
//
#include <hip/hip_runtime.h>

using f32x4  = __attribute__((ext_vector_type(4))) float;
using bf16x8 = __attribute__((ext_vector_type(8))) __bf16;
using u16x4  = __attribute__((ext_vector_type(4))) unsigned short;

#define BK 64
#define REG_HALF   8192      // ushorts: 128 rows x 64 cols
#define A_OFS      0
#define B_OFS      16384
#define BUF_STRIDE 32768     // one buffer = A(32KB)+B(32KB) = 64 KB

#define BARRIER() asm volatile("s_barrier" ::: "memory")
#define SGB()     __builtin_amdgcn_sched_barrier(0)

__device__ __forceinline__ unsigned short f32_to_bf16_bits(float f) {
    unsigned int u = __builtin_bit_cast(unsigned int, f);
    u = (u + 0x7fffu + ((u >> 16) & 1u)) >> 16;
    return (unsigned short)u;
}

__device__ __forceinline__ void gload_lds16(const void* g, void* l) {
    __builtin_amdgcn_global_load_lds(
        (const __attribute__((address_space(1))) unsigned int*)g,
        (__attribute__((address_space(3))) unsigned int*)l,
        16, 0, 0);
}

// ---------------------------------------------------------------------------
// Fake-quant x (exact-f32 math, bf16 store) and W f32->bf16. Unchanged.
// ---------------------------------------------------------------------------
__global__ void quant_kernel(const float* __restrict__ x,
                             unsigned short* __restrict__ xq,
                             int total4) {
    int idx = blockIdx.x * 256 + threadIdx.x;
    if (idx >= total4) return;
    f32x4 v = *(const f32x4*)(x + (size_t)idx * 4);
    float am = fmaxf(fmaxf(fabsf(v[0]), fabsf(v[1])),
                     fmaxf(fabsf(v[2]), fabsf(v[3])));
    am = fmaxf(am, __shfl_xor(am, 1));
    am = fmaxf(am, __shfl_xor(am, 2));
    am = fmaxf(am, __shfl_xor(am, 4));
    am = fmaxf(am, __shfl_xor(am, 8));
    float delta = fmaxf(am / 127.0f, 1e-5f);
    u16x4 o;
#pragma unroll
    for (int i = 0; i < 4; ++i) {
        float q = rintf(v[i] / delta);
        q = fminf(fmaxf(q, -127.0f), 127.0f);
        o[i] = f32_to_bf16_bits(q * delta);
    }
    *(u16x4*)(xq + (size_t)idx * 4) = o;
}

__global__ void wconv_kernel(const float* __restrict__ W,
                             unsigned short* __restrict__ Wb,
                             int total4) {
    int idx = blockIdx.x * 256 + threadIdx.x;
    if (idx >= total4) return;
    f32x4 v = *(const f32x4*)(W + (size_t)idx * 4);
    u16x4 o;
#pragma unroll
    for (int i = 0; i < 4; ++i) o[i] = f32_to_bf16_bits(v[i]);
    *(u16x4*)(Wb + (size_t)idx * 4) = o;
}

// Fragment readers (region base pointer; T2-swizzled column) ---------------
__device__ __forceinline__ void read_af(bf16x8 (&dst)[4][2],
    const unsigned short* reg, int wm, int lr, int lk, int sx) {
#pragma unroll
    for (int m = 0; m < 4; ++m)
#pragma unroll
        for (int kk = 0; kk < 2; ++kk)
            dst[m][kk] = *(const bf16x8*)(reg
                + (wm * 64 + m * 16 + lr) * 64 + ((((kk << 2) + lk) ^ sx) << 3));
}

__device__ __forceinline__ void read_bf(bf16x8 (&dst)[2][2],
    const unsigned short* reg, int wn, int lr, int lk, int sx) {
#pragma unroll
    for (int n = 0; n < 2; ++n)
#pragma unroll
        for (int kk = 0; kk < 2; ++kk)
            dst[n][kk] = *(const bf16x8*)(reg
                + (wn * 32 + n * 16 + lr) * 64 + ((((kk << 2) + lk) ^ sx) << 3));
}

__device__ __forceinline__ void mfma_quad(f32x4 (&acc)[8][4], int mo, int no,
    const bf16x8 (&af)[4][2], const bf16x8 (&bf)[2][2]) {
#pragma unroll
    for (int m = 0; m < 4; ++m)
#pragma unroll
        for (int n = 0; n < 2; ++n)
#pragma unroll
            for (int kk = 0; kk < 2; ++kk)
                acc[mo + m][no + n] = __builtin_amdgcn_mfma_f32_16x16x32_bf16(
                    af[m][kk], bf[n][kk], acc[mo + m][no + n], 0, 0, 0);
}

// ---------------------------------------------------------------------------
// 256x256 bf16 GEMM (B^T), 4-phase / 1-barrier-per-phase / lead-2 staging.
// Phase p: { reads_p issue ; 2x gload_lds (stage for tile t+2 into cb's
//            region that died at p-1) ; SGB ; setprio(1) 16 MFMA setprio(0) ;
//            [tile end: vmcnt(6)+lgkmcnt(0)+SGB] ; BARRIER }
// Stage stream (all -> cb, for tile t+2):  P1: B-h0  P2: A-h0  P3: B-h1
//   P4: A-h1.  Region deaths: B-h0 dead all tile (rotation-read at t-1 P4,
//   drained by t-1's tile-end lgkmcnt(0)); A-h0 dies P1; B-h1 dies P2;
//   A-h1 dies P3. Every stage issues one phase after its region's death
//   barrier; all read-vs-stage region pairs within a phase are disjoint.
// vmcnt ledger (2 loads per phase-stage): before tile-end wait: s(t-1,P2..4)
//   [6] + s(t,P1..4) [8] = 14 -> vmcnt(6) retires 8, proving through
//   s(t,P1). Tile t+1 reads: afL<-s(t-1,P2), bfB<-s(t-1,P3), afH<-s(t-1,P4),
//   rotation bfA'<-s(t,P1): all proven. Prologue: t0{4} + t1:B-h0 + t1{3},
//   vmcnt(6) retires t0+t1:B-h0 -> matches steady state. Tail: stage source
//   clamped to NT-1 (writes land in dead regions; ledger exact).
// WAR safety without leading barriers: every wave's lgkm wait delivers its
// reads before its MFMA, hence before the phase barrier; stages issue after
// that barrier. Tile-end lgkmcnt(0) covers the rotation read (consumed 2
// phases later). Round-5 lesson: no deep reg rotation (128-VGPR cap).
// ---------------------------------------------------------------------------
__global__ __launch_bounds__(512, 2) void gemm_kernel(
    const unsigned short* __restrict__ A,   // [M][K] bf16 bits (quantized x)
    const unsigned short* __restrict__ B,   // [N][K] bf16 bits (W)
    const float* __restrict__ bias,         // [N]
    float* __restrict__ out,                // [M][N] f32
    int M, int N, int K)
{
    __shared__ unsigned short lds[2 * BUF_STRIDE];   // 128 KiB

    const int tid  = threadIdx.x;
    const int lane = tid & 63;
    const int wv   = tid >> 6;
    const int wm   = wv >> 2;        // 0..1  (128 rows each)
    const int wn   = wv & 3;         // 0..3  (64 cols each)
    const int lr   = lane & 15;
    const int lk   = lane >> 4;      // 0..3
    const int sx   = lr & 7;

    const int nbn = N / 256;
    const int nwg = gridDim.x;
    const int cpx = nwg >> 3;        // bijective XCD swizzle (nwg % 8 == 0)
    const int swz = (blockIdx.x & 7) * cpx + (blockIdx.x >> 3);
    const int bm0 = (swz / nbn) * 256;
    const int bn0 = (swz % nbn) * 256;

    const unsigned short* Ag = A + (size_t)bm0 * K;
    const unsigned short* Bg = B + (size_t)bn0 * K;
    const int NT = K / BK;           // 64, even

    // Hoisted per-lane staging offsets (element units, 32-bit safe: <1.1M).
    // g = it*512 + tid; gr = g>>3; c = ((g&7)^(gr&7))<<3 (T2 inverse swizzle)
    const int gr0 = tid >> 3,         gr1 = (512 + tid) >> 3;
    const int c0  = ((tid & 7) ^ (gr0 & 7)) << 3;
    const int c1  = ((tid & 7) ^ (gr1 & 7)) << 3;
    const int offA0 = ((((gr0 >> 6) << 7) + (gr0 & 63))) * K + c0;
    const int offA1 = ((((gr1 >> 6) << 7) + (gr1 & 63))) * K + c1;
    const int offB0 = ((((gr0 >> 5) << 6) + (gr0 & 31))) * K + c0;
    const int offB1 = ((((gr1 >> 5) << 6) + (gr1 & 31))) * K + c1;
    const int ldsu0 = tid * 8, ldsu1 = (512 + tid) * 8;

#define STAGE_AH0(TK, DST) { gload_lds16(Ag + offA0 + (TK), (DST) + ldsu0); \
                             gload_lds16(Ag + offA1 + (TK), (DST) + ldsu1); }
#define STAGE_AH1(TK, DST) { gload_lds16(Ag + offA0 + 64*K + (TK), (DST) + ldsu0); \
                             gload_lds16(Ag + offA1 + 64*K + (TK), (DST) + ldsu1); }
#define STAGE_BH0(TK, DST) { gload_lds16(Bg + offB0 + (TK), (DST) + ldsu0); \
                             gload_lds16(Bg + offB1 + (TK), (DST) + ldsu1); }
#define STAGE_BH1(TK, DST) { gload_lds16(Bg + offB0 + 32*K + (TK), (DST) + ldsu0); \
                             gload_lds16(Bg + offB1 + 32*K + (TK), (DST) + ldsu1); }

    f32x4 acc[8][4] = {};

    // Prologue: t0 full -> buf0; then t1 B-h0 FIRST, then t1 rest -> buf1.
    STAGE_AH0(0, lds + A_OFS);
    STAGE_BH1(0, lds + B_OFS + REG_HALF);
    STAGE_AH1(0, lds + A_OFS + REG_HALF);
    STAGE_BH0(0, lds + B_OFS);
    STAGE_BH0(BK, lds + BUF_STRIDE + B_OFS);
    STAGE_AH0(BK, lds + BUF_STRIDE + A_OFS);
    STAGE_BH1(BK, lds + BUF_STRIDE + B_OFS + REG_HALF);
    STAGE_AH1(BK, lds + BUF_STRIDE + A_OFS + REG_HALF);
    asm volatile("s_waitcnt vmcnt(6)" ::: "memory");  // t0 + t1:B-h0 proven
    BARRIER();

    bf16x8 bfA_e[2][2], bfA_o[2][2];
    read_bf(bfA_e, lds + B_OFS, wn, lr, lk, sx);      // bfA(0) -> regs
    asm volatile("s_waitcnt lgkmcnt(0)" ::: "memory");
    SGB();
    BARRIER();

#define TILE_ITER(T, CB, NB, BFA_IN, BFA_OUT)                                  \
    {                                                                          \
        unsigned short* cb_ = (CB);                                            \
        unsigned short* nb_ = (NB);                                            \
        const int tk2 = (((T) + 2 < NT) ? (T) + 2 : NT - 1) * BK;              \
        bf16x8 afL_[4][2], afH_[4][2], bfB_[2][2];                             \
        /* P1: Q1 = afL x bfA_in ; stage B-h0(t+2)->cb */                      \
        read_af(afL_, cb_ + A_OFS, wm, lr, lk, sx);                            \
        STAGE_BH0(tk2, cb_ + B_OFS);                                           \
        SGB();                                                                 \
        __builtin_amdgcn_s_setprio(1);                                         \
        mfma_quad(acc, 0, 0, afL_, BFA_IN);                                    \
        __builtin_amdgcn_s_setprio(0);                                         \
        BARRIER();                                                             \
        /* P2: Q2 = afL x bfB ; stage A-h0(t+2)->cb */                         \
        read_bf(bfB_, cb_ + B_OFS + REG_HALF, wn, lr, lk, sx);                 \
        STAGE_AH0(tk2, cb_ + A_OFS);                                           \
        SGB();                                                                 \
        __builtin_amdgcn_s_setprio(1);                                         \
        mfma_quad(acc, 0, 2, afL_, bfB_);                                      \
        __builtin_amdgcn_s_setprio(0);                                         \
        BARRIER();                                                             \
        /* P3: Q3 = afH x bfA_in ; stage B-h1(t+2)->cb */                      \
        read_af(afH_, cb_ + A_OFS + REG_HALF, wm, lr, lk, sx);                 \
        STAGE_BH1(tk2, cb_ + B_OFS + REG_HALF);                                \
        SGB();                                                                 \
        __builtin_amdgcn_s_setprio(1);                                         \
        mfma_quad(acc, 4, 0, afH_, BFA_IN);                                    \
        __builtin_amdgcn_s_setprio(0);                                         \
        BARRIER();                                                             \
        /* P4: Q4 = afH x bfB ; rotate bfA' = B-h0(t+1) from nb ;              \
               stage A-h1(t+2)->cb ; single tile-end waits */                  \
        read_bf(BFA_OUT, nb_ + B_OFS, wn, lr, lk, sx);                         \
        STAGE_AH1(tk2, cb_ + A_OFS + REG_HALF);                                \
        SGB();                                                                 \
        __builtin_amdgcn_s_setprio(1);                                         \
        mfma_quad(acc, 4, 2, afH_, bfB_);                                      \
        __builtin_amdgcn_s_setprio(0);                                         \
        asm volatile("s_waitcnt vmcnt(6)" ::: "memory");                       \
        asm volatile("s_waitcnt lgkmcnt(0)" ::: "memory");                     \
        SGB();                                                                 \
        BARRIER();                                                             \
    }

    for (int tt = 0; tt < NT; tt += 2) {
        TILE_ITER(tt,     lds,              lds + BUF_STRIDE, bfA_e, bfA_o);
        TILE_ITER(tt + 1, lds + BUF_STRIDE, lds,              bfA_o, bfA_e);
    }
#undef TILE_ITER
#undef STAGE_AH0
#undef STAGE_AH1
#undef STAGE_BH0
#undef STAGE_BH1

    // Epilogue: C/D layout col = lane&15, row = (lane>>4)*4 + j  [m89]
    const int r0   = bm0 + wm * 128;
    const int cC0  = bn0 + wn * 64;
    const int rsub = lk << 2;
#pragma unroll
    for (int nf = 0; nf < 4; ++nf) {
        int col = cC0 + nf * 16 + lr;
        float bv = bias[col];
#pragma unroll
        for (int mf = 0; mf < 8; ++mf) {
            int row = r0 + mf * 16 + rsub;
#pragma unroll
            for (int j = 0; j < 4; ++j)
                out[(size_t)(row + j) * N + col] = acc[mf][nf][j] + bv;
        }
    }
}

extern "C" void kernel_launch(void* const* d_in, const int* in_sizes, int n_in,
                              void* d_out, int out_size, void* d_ws, size_t ws_size,
                              hipStream_t stream) {
    const float* x = (const float*)d_in[0];   // [M][K] f32
    const float* W = (const float*)d_in[1];   // [N][K] f32
    const float* b = (const float*)d_in[2];   // [N]   f32
    float* out = (float*)d_out;               // [M][N] f32

    const int N = in_sizes[2];                // 4096
    const int K = in_sizes[1] / N;            // 4096
    const int M = in_sizes[0] / K;            // 8192

    unsigned short* xq = (unsigned short*)d_ws;            // 64 MB
    unsigned short* Wb = xq + (size_t)M * K;               // 32 MB

    const int t4x = (int)(((long long)M * K) / 4);
    quant_kernel<<<(t4x + 255) / 256, 256, 0, stream>>>(x, xq, t4x);
    const int t4w = (int)(((long long)N * K) / 4);
    wconv_kernel<<<(t4w + 255) / 256, 256, 0, stream>>>(W, Wb, t4w);

    dim3 grid((M / 256) * (N / 256));         // 512 blocks
    gemm_kernel<<<grid, 512, 0, stream>>>(xq, Wb, b, out, M, N, K);
}

// Round 8
// 275.209 us; speedup vs baseline: 5.1979x; 1.0002x over previous
//
#include <hip/hip_runtime.h>

using f32x4  = __attribute__((ext_vector_type(4))) float;
using bf16x8 = __attribute__((ext_vector_type(8))) __bf16;
using u16x4  = __attribute__((ext_vector_type(4))) unsigned short;

#define BK 64
#define REG_HALF   8192      // ushorts: 128 rows x 64 cols
#define A_OFS      0
#define B_OFS      16384
#define BUF_STRIDE 32768     // one buffer = A(32KB)+B(32KB) = 64 KB

#define BARRIER() __builtin_amdgcn_s_barrier()
#define SGB()     __builtin_amdgcn_sched_barrier(0)

__device__ __forceinline__ unsigned short f32_to_bf16_bits(float f) {
    unsigned int u = __builtin_bit_cast(unsigned int, f);
    u = (u + 0x7fffu + ((u >> 16) & 1u)) >> 16;
    return (unsigned short)u;
}

__device__ __forceinline__ void gload_lds16(const void* g, void* l) {
    __builtin_amdgcn_global_load_lds(
        (const __attribute__((address_space(1))) unsigned int*)g,
        (__attribute__((address_space(3))) unsigned int*)l,
        16, 0, 0);
}

// ---------------------------------------------------------------------------
// Fake-quant x (exact-f32 math, bf16 store) and W f32->bf16. Unchanged.
// ---------------------------------------------------------------------------
__global__ void quant_kernel(const float* __restrict__ x,
                             unsigned short* __restrict__ xq,
                             int total4) {
    int idx = blockIdx.x * 256 + threadIdx.x;
    if (idx >= total4) return;
    f32x4 v = *(const f32x4*)(x + (size_t)idx * 4);
    float am = fmaxf(fmaxf(fabsf(v[0]), fabsf(v[1])),
                     fmaxf(fabsf(v[2]), fabsf(v[3])));
    am = fmaxf(am, __shfl_xor(am, 1));
    am = fmaxf(am, __shfl_xor(am, 2));
    am = fmaxf(am, __shfl_xor(am, 4));
    am = fmaxf(am, __shfl_xor(am, 8));
    float delta = fmaxf(am / 127.0f, 1e-5f);
    u16x4 o;
#pragma unroll
    for (int i = 0; i < 4; ++i) {
        float q = rintf(v[i] / delta);
        q = fminf(fmaxf(q, -127.0f), 127.0f);
        o[i] = f32_to_bf16_bits(q * delta);
    }
    *(u16x4*)(xq + (size_t)idx * 4) = o;
}

__global__ void wconv_kernel(const float* __restrict__ W,
                             unsigned short* __restrict__ Wb,
                             int total4) {
    int idx = blockIdx.x * 256 + threadIdx.x;
    if (idx >= total4) return;
    f32x4 v = *(const f32x4*)(W + (size_t)idx * 4);
    u16x4 o;
#pragma unroll
    for (int i = 0; i < 4; ++i) o[i] = f32_to_bf16_bits(v[i]);
    *(u16x4*)(Wb + (size_t)idx * 4) = o;
}

// Fragment readers (region base pointer; T2-swizzled column) ---------------
__device__ __forceinline__ void read_af(bf16x8 (&dst)[4][2],
    const unsigned short* reg, int wm, int lr, int lk, int sx) {
#pragma unroll
    for (int m = 0; m < 4; ++m)
#pragma unroll
        for (int kk = 0; kk < 2; ++kk)
            dst[m][kk] = *(const bf16x8*)(reg
                + (wm * 64 + m * 16 + lr) * 64 + ((((kk << 2) + lk) ^ sx) << 3));
}

__device__ __forceinline__ void read_bf(bf16x8 (&dst)[2][2],
    const unsigned short* reg, int wn, int lr, int lk, int sx) {
#pragma unroll
    for (int n = 0; n < 2; ++n)
#pragma unroll
        for (int kk = 0; kk < 2; ++kk)
            dst[n][kk] = *(const bf16x8*)(reg
                + (wn * 32 + n * 16 + lr) * 64 + ((((kk << 2) + lk) ^ sx) << 3));
}

__device__ __forceinline__ void mfma_quad(f32x4 (&acc)[8][4], int mo, int no,
    const bf16x8 (&af)[4][2], const bf16x8 (&bf)[2][2]) {
#pragma unroll
    for (int m = 0; m < 4; ++m)
#pragma unroll
        for (int n = 0; n < 2; ++n)
#pragma unroll
            for (int kk = 0; kk < 2; ++kk)
                acc[mo + m][no + n] = __builtin_amdgcn_mfma_f32_16x16x32_bf16(
                    af[m][kk], bf[n][kk], acc[mo + m][no + n], 0, 0, 0);
}

// ---------------------------------------------------------------------------
// 256x256 bf16 GEMM (B^T), barrier-BEFORE-MFMA schedule (m201 arrangement):
// Phase p: { reads_p ; stage_p ; SGB ; BARRIER ; setprio(1) MFMA_p
//            setprio(0) ; SGB }  — barrier rendezvous absorbs ds_read
// delivery; MFMA starts with data resident. SGBs pin MFMA between its
// barrier and the next phase's reads (register-only MFMA could otherwise
// sink across barriers and void the WAR proofs).
// Stage stream: P1: A-h1(t+1)->nb, P2: B-h0(t+2)->cb, P3: A-h0(t+2)->cb,
//               P4: B-h1(t+2)->cb.
// WAR proofs (stage_p may overwrite a region last read at p-2, since all
// waves passing B_{p-1} have executed M_{p-2} => its reads delivered):
//   P1: nb.A-h1 read (t-1).P3, M proven by B((t-1).P4) ✓
//   P2: cb.B-h0 rotation-read (t-1).P4, drained by tile-end lgkmcnt(0) ✓
//   P3: cb.A-h0 read t.P1, M(t.P1) proven by B(t.P2) ✓
//   P4: cb.B-h1 read t.P2, M(t.P2) proven by B(t.P3) ✓
// vmcnt ledger (1 stage call = 2 loads per phase, uniform): stage-to-read
// distance = 6 calls for every region; tile-end vmcnt(4) (after S(t.P4))
// retires through s(t).P2 = everything tile t+1 reads (incl. rotation
// B-h0(t+2) @ s(t).P2). Prologue issues 7 calls (B-h0(0), A-h0(0),
// B-h1(0), A-h1(0), B-h0(1), A-h0(1), B-h1(1)); vmcnt(4) retires the
// first 5 = exactly tile 0's reads + pre-loop rotation. Tail: sources
// clamped to NT-1 (writes land in dead regions, ledger uniform);
// vmcnt(0) at the last tile drains DMA before LDS dealloc.
// ---------------------------------------------------------------------------
__global__ __launch_bounds__(512, 2) void gemm_kernel(
    const unsigned short* __restrict__ A,   // [M][K] bf16 bits (quantized x)
    const unsigned short* __restrict__ B,   // [N][K] bf16 bits (W)
    const float* __restrict__ bias,         // [N]
    float* __restrict__ out,                // [M][N] f32
    int M, int N, int K)
{
    __shared__ unsigned short lds[2 * BUF_STRIDE];   // 128 KiB

    const int tid  = threadIdx.x;
    const int lane = tid & 63;
    const int wv   = tid >> 6;
    const int wm   = wv >> 2;        // 0..1  (128 rows each)
    const int wn   = wv & 3;         // 0..3  (64 cols each)
    const int lr   = lane & 15;
    const int lk   = lane >> 4;      // 0..3
    const int sx   = lr & 7;

    const int nbn = N / 256;
    const int nwg = gridDim.x;
    const int cpx = nwg >> 3;        // bijective XCD swizzle (nwg % 8 == 0)
    const int swz = (blockIdx.x & 7) * cpx + (blockIdx.x >> 3);
    const int bm0 = (swz / nbn) * 256;
    const int bn0 = (swz % nbn) * 256;

    const unsigned short* Ag = A + (size_t)bm0 * K;
    const unsigned short* Bg = B + (size_t)bn0 * K;
    const int NT = K / BK;           // 64, even

    // Hoisted per-lane staging offsets (element units, 32-bit safe).
    const int gr0 = tid >> 3,         gr1 = (512 + tid) >> 3;
    const int c0  = ((tid & 7) ^ (gr0 & 7)) << 3;
    const int c1  = ((tid & 7) ^ (gr1 & 7)) << 3;
    const int offA0 = ((((gr0 >> 6) << 7) + (gr0 & 63))) * K + c0;
    const int offA1 = ((((gr1 >> 6) << 7) + (gr1 & 63))) * K + c1;
    const int offB0 = ((((gr0 >> 5) << 6) + (gr0 & 31))) * K + c0;
    const int offB1 = ((((gr1 >> 5) << 6) + (gr1 & 31))) * K + c1;
    const int ldsu0 = tid * 8, ldsu1 = (512 + tid) * 8;

#define STAGE_AH0(TK, DST) { gload_lds16(Ag + offA0 + (TK), (DST) + ldsu0); \
                             gload_lds16(Ag + offA1 + (TK), (DST) + ldsu1); }
#define STAGE_AH1(TK, DST) { gload_lds16(Ag + offA0 + 64*K + (TK), (DST) + ldsu0); \
                             gload_lds16(Ag + offA1 + 64*K + (TK), (DST) + ldsu1); }
#define STAGE_BH0(TK, DST) { gload_lds16(Bg + offB0 + (TK), (DST) + ldsu0); \
                             gload_lds16(Bg + offB1 + (TK), (DST) + ldsu1); }
#define STAGE_BH1(TK, DST) { gload_lds16(Bg + offB0 + 32*K + (TK), (DST) + ldsu0); \
                             gload_lds16(Bg + offB1 + 32*K + (TK), (DST) + ldsu1); }

    f32x4 acc[8][4] = {};

    // Prologue (ledger order): c0..c6
    STAGE_BH0(0,  lds + B_OFS);                          // c0 B-h0(0)
    STAGE_AH0(0,  lds + A_OFS);                          // c1 A-h0(0)
    STAGE_BH1(0,  lds + B_OFS + REG_HALF);               // c2 B-h1(0)
    STAGE_AH1(0,  lds + A_OFS + REG_HALF);               // c3 A-h1(0)
    STAGE_BH0(BK, lds + BUF_STRIDE + B_OFS);             // c4 B-h0(1)
    STAGE_AH0(BK, lds + BUF_STRIDE + A_OFS);             // c5 A-h0(1)
    STAGE_BH1(BK, lds + BUF_STRIDE + B_OFS + REG_HALF);  // c6 B-h1(1)
    asm volatile("s_waitcnt vmcnt(4)" ::: "memory");     // c0..c4 proven
    SGB();
    BARRIER();

    bf16x8 bfA_e[2][2], bfA_o[2][2];
    read_bf(bfA_e, lds + B_OFS, wn, lr, lk, sx);         // rotation bfA(0)
    asm volatile("s_waitcnt lgkmcnt(0)" ::: "memory");
    SGB();
    BARRIER();                                           // plays B((t-1).P4)

#define TILE_ITER(T, CB, NB, BFA_IN, BFA_OUT)                                  \
    {                                                                          \
        unsigned short* cb_ = (CB);                                            \
        unsigned short* nb_ = (NB);                                            \
        const int tk1 = (((T) + 1 < NT) ? (T) + 1 : NT - 1) * BK;              \
        const int tk2 = (((T) + 2 < NT) ? (T) + 2 : NT - 1) * BK;              \
        bf16x8 afL_[4][2], afH_[4][2], bfB_[2][2];                             \
        /* P1 */                                                               \
        read_af(afL_, cb_ + A_OFS, wm, lr, lk, sx);                            \
        STAGE_AH1(tk1, nb_ + A_OFS + REG_HALF);                                \
        SGB(); BARRIER();                                                      \
        __builtin_amdgcn_s_setprio(1);                                         \
        mfma_quad(acc, 0, 0, afL_, BFA_IN);                                    \
        __builtin_amdgcn_s_setprio(0); SGB();                                  \
        /* P2 */                                                               \
        read_bf(bfB_, cb_ + B_OFS + REG_HALF, wn, lr, lk, sx);                 \
        STAGE_BH0(tk2, cb_ + B_OFS);                                           \
        SGB(); BARRIER();                                                      \
        __builtin_amdgcn_s_setprio(1);                                         \
        mfma_quad(acc, 0, 2, afL_, bfB_);                                      \
        __builtin_amdgcn_s_setprio(0); SGB();                                  \
        /* P3 */                                                               \
        read_af(afH_, cb_ + A_OFS + REG_HALF, wm, lr, lk, sx);                 \
        STAGE_AH0(tk2, cb_ + A_OFS);                                           \
        SGB(); BARRIER();                                                      \
        __builtin_amdgcn_s_setprio(1);                                         \
        mfma_quad(acc, 4, 0, afH_, BFA_IN);                                    \
        __builtin_amdgcn_s_setprio(0); SGB();                                  \
        /* P4: rotation read + tile-end waits BEFORE the barrier */            \
        read_bf(BFA_OUT, nb_ + B_OFS, wn, lr, lk, sx);                         \
        STAGE_BH1(tk2, cb_ + B_OFS + REG_HALF);                                \
        if ((T) + 1 < NT) asm volatile("s_waitcnt vmcnt(4)" ::: "memory");     \
        else              asm volatile("s_waitcnt vmcnt(0)" ::: "memory");     \
        asm volatile("s_waitcnt lgkmcnt(0)" ::: "memory");                     \
        SGB(); BARRIER();                                                      \
        __builtin_amdgcn_s_setprio(1);                                         \
        mfma_quad(acc, 4, 2, afH_, bfB_);                                      \
        __builtin_amdgcn_s_setprio(0); SGB();                                  \
    }

    for (int tt = 0; tt < NT; tt += 2) {
        TILE_ITER(tt,     lds,              lds + BUF_STRIDE, bfA_e, bfA_o);
        TILE_ITER(tt + 1, lds + BUF_STRIDE, lds,              bfA_o, bfA_e);
    }
#undef TILE_ITER
#undef STAGE_AH0
#undef STAGE_AH1
#undef STAGE_BH0
#undef STAGE_BH1

    // Epilogue: C/D layout col = lane&15, row = (lane>>4)*4 + j  [m89]
    const int r0   = bm0 + wm * 128;
    const int cC0  = bn0 + wn * 64;
    const int rsub = lk << 2;
#pragma unroll
    for (int nf = 0; nf < 4; ++nf) {
        int col = cC0 + nf * 16 + lr;
        float bv = bias[col];
#pragma unroll
        for (int mf = 0; mf < 8; ++mf) {
            int row = r0 + mf * 16 + rsub;
#pragma unroll
            for (int j = 0; j < 4; ++j)
                out[(size_t)(row + j) * N + col] = acc[mf][nf][j] + bv;
        }
    }
}

extern "C" void kernel_launch(void* const* d_in, const int* in_sizes, int n_in,
                              void* d_out, int out_size, void* d_ws, size_t ws_size,
                              hipStream_t stream) {
    const float* x = (const float*)d_in[0];   // [M][K] f32
    const float* W = (const float*)d_in[1];   // [N][K] f32
    const float* b = (const float*)d_in[2];   // [N]   f32
    float* out = (float*)d_out;               // [M][N] f32

    const int N = in_sizes[2];                // 4096
    const int K = in_sizes[1] / N;            // 4096
    const int M = in_sizes[0] / K;            // 8192

    unsigned short* xq = (unsigned short*)d_ws;            // 64 MB
    unsigned short* Wb = xq + (size_t)M * K;               // 32 MB

    const int t4x = (int)(((long long)M * K) / 4);
    quant_kernel<<<(t4x + 255) / 256, 256, 0, stream>>>(x, xq, t4x);
    const int t4w = (int)(((long long)N * K) / 4);
    wconv_kernel<<<(t4w + 255) / 256, 256, 0, stream>>>(W, Wb, t4w);

    dim3 grid((M / 256) * (N / 256));         // 512 blocks
    gemm_kernel<<<grid, 512, 0, stream>>>(xq, Wb, b, out, M, N, K);
}